// Round 1
// baseline (455.834 us; speedup 1.0000x reference)
//
#include <hip/hip_runtime.h>
#include <hip/hip_bf16.h>
#include <math.h>

typedef __bf16 bf16;
typedef bf16  bf16x8 __attribute__((ext_vector_type(8)));
typedef float f32x4  __attribute__((ext_vector_type(4)));

#define MFMA16(a,b,c) __builtin_amdgcn_mfma_f32_16x16x32_bf16(a,b,c,0,0,0)

__device__ __forceinline__ bf16x8 cvt8(const float4& a, const float4& b) {
  bf16x8 v;
  v[0]=(bf16)a.x; v[1]=(bf16)a.y; v[2]=(bf16)a.z; v[3]=(bf16)a.w;
  v[4]=(bf16)b.x; v[5]=(bf16)b.y; v[6]=(bf16)b.z; v[7]=(bf16)b.w;
  return v;
}

// ---------------- prep: fp32 weights -> bf16 ----------------
__global__ void prep_weights(const float* __restrict__ qkv_w, const float* __restrict__ proj_w,
                             const float* __restrict__ fc1_w, const float* __restrict__ fc2_w,
                             bf16* __restrict__ qkv_wb, bf16* __restrict__ proj_wb,
                             bf16* __restrict__ fc1_wb, bf16* __restrict__ fc2_wb) {
  int i = blockIdx.x * 256 + threadIdx.x;
  if (i < 196608) qkv_wb[i] = (bf16)qkv_w[i];
  if (i <  65536) proj_wb[i] = (bf16)proj_w[i];
  if (i < 262144) { fc1_wb[i] = (bf16)fc1_w[i]; fc2_wb[i] = (bf16)fc2_w[i]; }
}

// ---------------- prep: CPB MLP -> bias[8][64][64] ----------------
__global__ void prep_bias(const float* __restrict__ w1, const float* __restrict__ b1,
                          const float* __restrict__ w2, float* __restrict__ bias_g) {
  __shared__ float tab[225][8];
  const int t = threadIdx.x;
  if (t < 225) {
    const int a = t / 15, b = t % 15;
    const float g0 = (float)(a - 7) * (8.0f / 7.0f);
    const float g1 = (float)(b - 7) * (8.0f / 7.0f);
    const float t0 = copysignf(log2f(fabsf(g0) + 1.0f) * (1.0f/3.0f), g0);
    const float t1 = copysignf(log2f(fabsf(g1) + 1.0f) * (1.0f/3.0f), g1);
    float acc[8] = {0.f,0.f,0.f,0.f,0.f,0.f,0.f,0.f};
    for (int h = 0; h < 512; ++h) {
      float hv = t0 * w1[h*3 + 0] + t1 * w1[h*3 + 1] + b1[h];
      hv = fmaxf(hv, 0.0f);
#pragma unroll
      for (int j = 0; j < 8; ++j) acc[j] += hv * w2[j*512 + h];
    }
#pragma unroll
    for (int j = 0; j < 8; ++j) tab[t][j] = acc[j];
  }
  __syncthreads();
  for (int idx = t; idx < 8*64*64; idx += 256) {
    const int head = idx >> 12, i = (idx >> 6) & 63, j = idx & 63;
    const int dy = (i >> 3) - (j >> 3), dx = (i & 7) - (j & 7);
    const float v = tab[(dy + 7)*15 + (dx + 7)][head];
    bias_g[idx] = 16.0f / (1.0f + expf(-v));
  }
}

// ---------------- fused window attention + proj + LN1 + shortcut ----------------
// one block per (batch, window); 4 waves.
__launch_bounds__(256, 1)
__global__ void k_attn(const float* __restrict__ x,
                       const bf16* __restrict__ qkv_wb, const float* __restrict__ qkv_b,
                       const float* __restrict__ nq_w, const float* __restrict__ nk_w,
                       const bf16* __restrict__ proj_wb, const float* __restrict__ proj_b,
                       const float* __restrict__ n1w, const float* __restrict__ n1b,
                       const float* __restrict__ bias_g,
                       float* __restrict__ x1) {
  __shared__ __align__(16) unsigned char SM[131072];
  const int tid  = threadIdx.x;
  const int wv   = tid >> 6;
  const int lane = tid & 63;
  const int lm   = lane & 15;
  const int lg   = lane >> 4;
  const int lk   = lg << 3;
  const int blk  = blockIdx.x;
  const int b    = blk >> 6;
  const int win  = blk & 63;
  const int wy   = win >> 3, wx = win & 7;

  const int QA = 32768;   // q  [64][256] bf16 (col = h*32+d), swizzled; later y_all
  const int KA = 65536;   // k  [64][256] bf16 ; later y2 fp32 [64][256] spans KA..KA+64K
  const int VT = 98304;   // v^T [8][32][64] bf16, swizzle keyed on d
  const int Y2 = 65536;

  // ---- stage shifted-window x tile -> bf16 LDS [64][256], XOR-swizzled
  {
    const int t = tid >> 2, q = tid & 3;
    const int iy = t >> 3, ix = t & 7;
    const int gh = (wy*8 + iy + 4) & 63, gw = (wx*8 + ix + 4) & 63;
    const float* src = x + (size_t)(b*4096 + gh*64 + gw) * 256 + q*64;
#pragma unroll
    for (int i = 0; i < 8; ++i) {
      float4 f0 = *(const float4*)(src + i*8);
      float4 f1 = *(const float4*)(src + i*8 + 4);
      *(bf16x8*)(SM + ((t*512 + (q*64 + i*8)*2) ^ ((t&7)<<4))) = cvt8(f0, f1);
    }
  }
  __syncthreads();

  // ---- QKV GEMM: 64x768 = xt(64x256) @ qkv_w^T ; wave covers 192 cols
#pragma unroll 1
  for (int ch = 0; ch < 3; ++ch) {
    const int colbase = wv*192 + ch*64;
    f32x4 acc[4][4] = {};
#pragma unroll
    for (int kk = 0; kk < 8; ++kk) {
      const int ko = kk*32 + lk;
      bf16x8 a[4], bb[4];
#pragma unroll
      for (int m = 0; m < 4; ++m) {
        const int t = m*16 + lm;
        a[m] = *(const bf16x8*)(SM + ((t*512 + ko*2) ^ ((t&7)<<4)));
      }
#pragma unroll
      for (int n = 0; n < 4; ++n) {
        const int j = colbase + n*16 + lm;
        bb[n] = *(const bf16x8*)(qkv_wb + j*256 + ko);
      }
#pragma unroll
      for (int m = 0; m < 4; ++m)
#pragma unroll
        for (int n = 0; n < 4; ++n)
          acc[m][n] = MFMA16(a[m], bb[n], acc[m][n]);
    }
#pragma unroll
    for (int n = 0; n < 4; ++n) {
      const int j = colbase + n*16 + lm;
      const float bj = qkv_b[j];
#pragma unroll
      for (int m = 0; m < 4; ++m)
#pragma unroll
        for (int r = 0; r < 4; ++r) {
          const int t = m*16 + lg*4 + r;
          const float v = acc[m][n][r] + bj;
          if (j < 256) {
            *(bf16*)(SM + QA + ((t*512 + j*2) ^ ((t&7)<<4))) = (bf16)v;
          } else if (j < 512) {
            const int jj = j - 256;
            *(bf16*)(SM + KA + ((t*512 + jj*2) ^ ((t&7)<<4))) = (bf16)v;
          } else {
            const int jj = j - 512;
            const int hh = jj >> 5, d = jj & 31;
            *(bf16*)(SM + VT + hh*4096 + ((d*128 + t*2) ^ ((d&7)<<4))) = (bf16)v;
          }
        }
    }
  }
  __syncthreads();

  // ---- per-(token,head) RMSNorm on q and k (1024 jobs / 256 threads)
#pragma unroll 1
  for (int p = tid; p < 1024; p += 256) {
    const int isk = p >> 9;
    const int pp  = p & 511;
    const int t = pp >> 3, hh = pp & 7;
    const int base = isk ? KA : QA;
    const float* nw = isk ? nk_w : nq_w;
    bf16x8 vv[4];
    float ssq = 0.f;
#pragma unroll
    for (int c = 0; c < 4; ++c) {
      vv[c] = *(const bf16x8*)(SM + base + ((t*512 + (hh*32 + c*8)*2) ^ ((t&7)<<4)));
#pragma unroll
      for (int e = 0; e < 8; ++e) { const float f = (float)vv[c][e]; ssq += f*f; }
    }
    const float sc = rsqrtf(ssq * (1.0f/32.0f) + 1.1920929e-07f);
#pragma unroll
    for (int c = 0; c < 4; ++c) {
      bf16x8 o;
#pragma unroll
      for (int e = 0; e < 8; ++e) o[e] = (bf16)((float)vv[c][e] * sc * nw[c*8 + e]);
      *(bf16x8*)(SM + base + ((t*512 + (hh*32 + c*8)*2) ^ ((t&7)<<4))) = o;
    }
  }
  __syncthreads();

  // ---- attention: wave handles heads {wv, wv+4}
  f32x4 yacc[2][4][2];
  {
    const int PB = wv * 8192;   // wave-private P buffer [64][64] bf16 in dead xt area
#pragma unroll 1
    for (int hi = 0; hi < 2; ++hi) {
      const int h = wv + hi*4;
      bf16x8 qf[4], kf[4];
#pragma unroll
      for (int m = 0; m < 4; ++m)
        qf[m] = *(const bf16x8*)(SM + QA + (((m*16+lm)*512 + (h*32+lk)*2) ^ ((lm&7)<<4)));
#pragma unroll
      for (int n = 0; n < 4; ++n)
        kf[n] = *(const bf16x8*)(SM + KA + (((n*16+lm)*512 + (h*32+lk)*2) ^ ((lm&7)<<4)));
      f32x4 s[4][4];
#pragma unroll
      for (int m = 0; m < 4; ++m)
#pragma unroll
        for (int n = 0; n < 4; ++n) {
          f32x4 z = {};
          s[m][n] = MFMA16(qf[m], kf[n], z);
        }
      // bias + shift mask (region-id equality)
#pragma unroll
      for (int n = 0; n < 4; ++n) {
        const int ct = n*16 + lm;
        const int idc = ((wy==7) ? (((ct>>3) < 4) ? 1 : 2) : 0) * 3
                      + ((wx==7) ? (((ct&7)  < 4) ? 1 : 2) : 0);
#pragma unroll
        for (int m = 0; m < 4; ++m)
#pragma unroll
          for (int r = 0; r < 4; ++r) {
            const int rt = m*16 + lg*4 + r;
            const int idr = ((wy==7) ? (((rt>>3) < 4) ? 1 : 2) : 0) * 3
                          + ((wx==7) ? (((rt&7)  < 4) ? 1 : 2) : 0);
            float add = bias_g[h*4096 + rt*64 + ct];
            if (idr != idc) add -= 100.0f;
            s[m][n][r] += add;
          }
      }
      // row softmax (row lives in one 16-lane group, reg r, across 4 n-frags)
#pragma unroll
      for (int m = 0; m < 4; ++m)
#pragma unroll
        for (int r = 0; r < 4; ++r) {
          float v0 = s[m][0][r], v1 = s[m][1][r], v2 = s[m][2][r], v3 = s[m][3][r];
          float mx = fmaxf(fmaxf(v0, v1), fmaxf(v2, v3));
          mx = fmaxf(mx, __shfl_xor(mx, 1));
          mx = fmaxf(mx, __shfl_xor(mx, 2));
          mx = fmaxf(mx, __shfl_xor(mx, 4));
          mx = fmaxf(mx, __shfl_xor(mx, 8));
          v0 = expf(v0 - mx); v1 = expf(v1 - mx); v2 = expf(v2 - mx); v3 = expf(v3 - mx);
          float sm = v0 + v1 + v2 + v3;
          sm += __shfl_xor(sm, 1);
          sm += __shfl_xor(sm, 2);
          sm += __shfl_xor(sm, 4);
          sm += __shfl_xor(sm, 8);
          const float inv = 1.0f / sm;
          s[m][0][r] = v0*inv; s[m][1][r] = v1*inv; s[m][2][r] = v2*inv; s[m][3][r] = v3*inv;
        }
      // P -> bf16 wave-private LDS
#pragma unroll
      for (int m = 0; m < 4; ++m)
#pragma unroll
        for (int n = 0; n < 4; ++n)
#pragma unroll
          for (int r = 0; r < 4; ++r) {
            const int rt = m*16 + lg*4 + r, ct = n*16 + lm;
            *(bf16*)(SM + PB + ((rt*128 + ct*2) ^ ((rt&7)<<4))) = (bf16)s[m][n][r];
          }
      // PV
#pragma unroll
      for (int m = 0; m < 4; ++m)
#pragma unroll
        for (int nf = 0; nf < 2; ++nf) { f32x4 z = {}; yacc[hi][m][nf] = z; }
#pragma unroll
      for (int ks = 0; ks < 2; ++ks) {
        bf16x8 pa[4], vb[2];
#pragma unroll
        for (int m = 0; m < 4; ++m) {
          const int rt = m*16 + lm;
          pa[m] = *(const bf16x8*)(SM + PB + ((rt*128 + (ks*32+lk)*2) ^ ((lm&7)<<4)));
        }
#pragma unroll
        for (int nf = 0; nf < 2; ++nf) {
          const int d = nf*16 + lm;
          vb[nf] = *(const bf16x8*)(SM + VT + h*4096 + ((d*128 + (ks*32+lk)*2) ^ ((d&7)<<4)));
        }
#pragma unroll
        for (int m = 0; m < 4; ++m)
#pragma unroll
          for (int nf = 0; nf < 2; ++nf)
            yacc[hi][m][nf] = MFMA16(pa[m], vb[nf], yacc[hi][m][nf]);
      }
    }
  }
  __syncthreads();   // everyone done reading q/k/v

  // ---- y_all (64x256 bf16) into QA area
#pragma unroll
  for (int hi = 0; hi < 2; ++hi) {
    const int h = wv + hi*4;
#pragma unroll
    for (int m = 0; m < 4; ++m)
#pragma unroll
      for (int nf = 0; nf < 2; ++nf)
#pragma unroll
        for (int r = 0; r < 4; ++r) {
          const int t = m*16 + lg*4 + r;
          const int c = h*32 + nf*16 + lm;
          *(bf16*)(SM + QA + ((t*512 + c*2) ^ ((t&7)<<4))) = (bf16)yacc[hi][m][nf][r];
        }
  }
  __syncthreads();

  // ---- proj: 64x256 = y_all @ proj_w^T ; wave covers 64 cols
  {
    f32x4 acc[4][4] = {};
#pragma unroll
    for (int kk = 0; kk < 8; ++kk) {
      const int ko = kk*32 + lk;
      bf16x8 a[4], bb[4];
#pragma unroll
      for (int m = 0; m < 4; ++m) {
        const int t = m*16 + lm;
        a[m] = *(const bf16x8*)(SM + QA + ((t*512 + ko*2) ^ ((t&7)<<4)));
      }
#pragma unroll
      for (int n = 0; n < 4; ++n) {
        const int j = wv*64 + n*16 + lm;
        bb[n] = *(const bf16x8*)(proj_wb + j*256 + ko);
      }
#pragma unroll
      for (int m = 0; m < 4; ++m)
#pragma unroll
        for (int n = 0; n < 4; ++n)
          acc[m][n] = MFMA16(a[m], bb[n], acc[m][n]);
    }
#pragma unroll
    for (int n = 0; n < 4; ++n) {
      const int j = wv*64 + n*16 + lm;
      const float bj = proj_b[j];
#pragma unroll
      for (int m = 0; m < 4; ++m)
#pragma unroll
        for (int r = 0; r < 4; ++r) {
          const int t = m*16 + lg*4 + r;
          *(float*)(SM + Y2 + t*1024 + j*4) = acc[m][n][r] + bj;
        }
    }
  }
  __syncthreads();

  // ---- LN(norm1) + shortcut, scatter to x1 at unshifted position
  {
    const int t = tid >> 2, q = tid & 3;
    const float* row = (const float*)(SM + Y2 + t*1024) + q*64;
    float sum = 0.f, ssq = 0.f;
#pragma unroll
    for (int i = 0; i < 16; ++i) {
      float4 f = *(const float4*)(row + i*4);
      sum += f.x + f.y + f.z + f.w;
      ssq += f.x*f.x + f.y*f.y + f.z*f.z + f.w*f.w;
    }
    sum += __shfl_xor(sum, 1); sum += __shfl_xor(sum, 2);
    ssq += __shfl_xor(ssq, 1); ssq += __shfl_xor(ssq, 2);
    const float mu  = sum * (1.0f/256.0f);
    const float var = ssq * (1.0f/256.0f) - mu*mu;
    const float inv = rsqrtf(var + 1e-5f);
    const int iy = t >> 3, ix = t & 7;
    const int gh = (wy*8 + iy + 4) & 63, gw = (wx*8 + ix + 4) & 63;
    const size_t grow = (size_t)(b*4096 + gh*64 + gw) * 256;
#pragma unroll
    for (int i = 0; i < 16; ++i) {
      float4 f = *(const float4*)(row + i*4);
      const int c = q*64 + i*4;
      float4 o;
      o.x = (f.x - mu)*inv*n1w[c+0] + n1b[c+0] + x[grow + c + 0];
      o.y = (f.y - mu)*inv*n1w[c+1] + n1b[c+1] + x[grow + c + 1];
      o.z = (f.z - mu)*inv*n1w[c+2] + n1b[c+2] + x[grow + c + 2];
      o.w = (f.w - mu)*inv*n1w[c+3] + n1b[c+3] + x[grow + c + 3];
      *(float4*)(x1 + grow + c) = o;
    }
  }
}

// ---------------- fc1 + exact GELU -> h (bf16) ----------------
__launch_bounds__(256, 2)
__global__ void k_fc1(const float* __restrict__ x1, const bf16* __restrict__ fc1_wb,
                      const float* __restrict__ fc1_b, bf16* __restrict__ h) {
  __shared__ __align__(16) unsigned char SM[65536];
  const int tid = threadIdx.x;
  const int wv = tid >> 6, lane = tid & 63;
  const int lm = lane & 15, lg = lane >> 4, lk = lg << 3;
  const int mb = blockIdx.x, nb = blockIdx.y;
  {
    const int t = tid >> 2, q = tid & 3;
    const float* src = x1 + (size_t)(mb*64 + t) * 256 + q*64;
#pragma unroll
    for (int i = 0; i < 8; ++i) {
      float4 f0 = *(const float4*)(src + i*8);
      float4 f1 = *(const float4*)(src + i*8 + 4);
      *(bf16x8*)(SM + ((t*512 + (q*64 + i*8)*2) ^ ((t&7)<<4))) = cvt8(f0, f1);
    }
  }
  __syncthreads();
  f32x4 acc[4][4] = {};
#pragma unroll
  for (int kk = 0; kk < 8; ++kk) {
    const int ko = kk*32 + lk;
    bf16x8 a[4], bb[4];
#pragma unroll
    for (int m = 0; m < 4; ++m) {
      const int t = m*16 + lm;
      a[m] = *(const bf16x8*)(SM + ((t*512 + ko*2) ^ ((t&7)<<4)));
    }
#pragma unroll
    for (int n = 0; n < 4; ++n) {
      const int j = nb*256 + wv*64 + n*16 + lm;
      bb[n] = *(const bf16x8*)(fc1_wb + (size_t)j*256 + ko);
    }
#pragma unroll
    for (int m = 0; m < 4; ++m)
#pragma unroll
      for (int n = 0; n < 4; ++n)
        acc[m][n] = MFMA16(a[m], bb[n], acc[m][n]);
  }
  __syncthreads();
  // GELU + stage to LDS out area for coalesced global store
#pragma unroll
  for (int n = 0; n < 4; ++n) {
    const int j  = nb*256 + wv*64 + n*16 + lm;
    const int jj = wv*64 + n*16 + lm;
    const float bj = fc1_b[j];
#pragma unroll
    for (int m = 0; m < 4; ++m)
#pragma unroll
      for (int r = 0; r < 4; ++r) {
        const int t = m*16 + lg*4 + r;
        float v = acc[m][n][r] + bj;
        v = 0.5f * v * (1.0f + erff(v * 0.70710678118654752f));
        *(bf16*)(SM + 32768 + ((t*512 + jj*2) ^ ((t&7)<<4))) = (bf16)v;
      }
  }
  __syncthreads();
  {
    const int t = tid >> 2, q = tid & 3;
    bf16* dst = h + (size_t)(mb*64 + t) * 1024 + nb*256 + q*64;
#pragma unroll
    for (int i = 0; i < 8; ++i) {
      bf16x8 v = *(const bf16x8*)(SM + 32768 + ((t*512 + (q*64 + i*8)*2) ^ ((t&7)<<4)));
      *(bf16x8*)(dst + i*8) = v;
    }
  }
}

// ---------------- fc2 + LN(norm2) + residual -> out ----------------
__launch_bounds__(256, 1)
__global__ void k_fc2(const float* __restrict__ x1, const bf16* __restrict__ h,
                      const bf16* __restrict__ fc2_wb, const float* __restrict__ fc2_b,
                      const float* __restrict__ n2w, const float* __restrict__ n2b,
                      float* __restrict__ out) {
  __shared__ __align__(16) unsigned char SM[98304];   // 32K stage + 64K y2
  const int tid = threadIdx.x;
  const int wv = tid >> 6, lane = tid & 63;
  const int lm = lane & 15, lg = lane >> 4, lk = lg << 3;
  const int mb = blockIdx.x;
  f32x4 acc[4][4] = {};
#pragma unroll 1
  for (int kc = 0; kc < 4; ++kc) {
    {
      const int t = tid >> 2, q = tid & 3;
      const bf16* src = h + (size_t)(mb*64 + t) * 1024 + kc*256 + q*64;
#pragma unroll
      for (int i = 0; i < 8; ++i) {
        bf16x8 v = *(const bf16x8*)(src + i*8);
        *(bf16x8*)(SM + ((t*512 + (q*64 + i*8)*2) ^ ((t&7)<<4))) = v;
      }
    }
    __syncthreads();
#pragma unroll
    for (int kk = 0; kk < 8; ++kk) {
      const int ko = kk*32 + lk;
      bf16x8 a[4], bb[4];
#pragma unroll
      for (int m = 0; m < 4; ++m) {
        const int t = m*16 + lm;
        a[m] = *(const bf16x8*)(SM + ((t*512 + ko*2) ^ ((t&7)<<4)));
      }
#pragma unroll
      for (int n = 0; n < 4; ++n) {
        const int j = wv*64 + n*16 + lm;
        bb[n] = *(const bf16x8*)(fc2_wb + (size_t)j*1024 + kc*256 + ko);
      }
#pragma unroll
      for (int m = 0; m < 4; ++m)
#pragma unroll
        for (int n = 0; n < 4; ++n)
          acc[m][n] = MFMA16(a[m], bb[n], acc[m][n]);
    }
    __syncthreads();
  }
#pragma unroll
  for (int n = 0; n < 4; ++n) {
    const int j = wv*64 + n*16 + lm;
    const float bj = fc2_b[j];
#pragma unroll
    for (int m = 0; m < 4; ++m)
#pragma unroll
      for (int r = 0; r < 4; ++r) {
        const int t = m*16 + lg*4 + r;
        *(float*)(SM + 32768 + t*1024 + j*4) = acc[m][n][r] + bj;
      }
  }
  __syncthreads();
  {
    const int t = tid >> 2, q = tid & 3;
    const float* row = (const float*)(SM + 32768 + t*1024) + q*64;
    float sum = 0.f, ssq = 0.f;
#pragma unroll
    for (int i = 0; i < 16; ++i) {
      float4 f = *(const float4*)(row + i*4);
      sum += f.x + f.y + f.z + f.w;
      ssq += f.x*f.x + f.y*f.y + f.z*f.z + f.w*f.w;
    }
    sum += __shfl_xor(sum, 1); sum += __shfl_xor(sum, 2);
    ssq += __shfl_xor(ssq, 1); ssq += __shfl_xor(ssq, 2);
    const float mu  = sum * (1.0f/256.0f);
    const float var = ssq * (1.0f/256.0f) - mu*mu;
    const float inv = rsqrtf(var + 1e-5f);
    const size_t grow = (size_t)(mb*64 + t) * 256;
#pragma unroll
    for (int i = 0; i < 16; ++i) {
      float4 f = *(const float4*)(row + i*4);
      const int c = q*64 + i*4;
      float4 o;
      o.x = (f.x - mu)*inv*n2w[c+0] + n2b[c+0] + x1[grow + c + 0];
      o.y = (f.y - mu)*inv*n2w[c+1] + n2b[c+1] + x1[grow + c + 1];
      o.z = (f.z - mu)*inv*n2w[c+2] + n2b[c+2] + x1[grow + c + 2];
      o.w = (f.w - mu)*inv*n2w[c+3] + n2b[c+3] + x1[grow + c + 3];
      *(float4*)(out + grow + c) = o;
    }
  }
}

extern "C" void kernel_launch(void* const* d_in, const int* in_sizes, int n_in,
                              void* d_out, int out_size, void* d_ws, size_t ws_size,
                              hipStream_t stream) {
  const float* x      = (const float*)d_in[0];
  const float* qkv_w  = (const float*)d_in[1];
  const float* qkv_b  = (const float*)d_in[2];
  const float* nq_w   = (const float*)d_in[3];
  const float* nk_w   = (const float*)d_in[4];
  const float* cpb_w1 = (const float*)d_in[5];
  const float* cpb_b1 = (const float*)d_in[6];
  const float* cpb_w2 = (const float*)d_in[7];
  const float* proj_w = (const float*)d_in[8];
  const float* proj_b = (const float*)d_in[9];
  const float* n1w    = (const float*)d_in[10];
  const float* n1b    = (const float*)d_in[11];
  const float* fc1_w  = (const float*)d_in[12];
  const float* fc1_b  = (const float*)d_in[13];
  const float* fc2_w  = (const float*)d_in[14];
  const float* fc2_b  = (const float*)d_in[15];
  const float* n2w    = (const float*)d_in[16];
  const float* n2b    = (const float*)d_in[17];

  char* ws = (char*)d_ws;
  float* x1      = (float*)(ws);                   // 33554432 B
  bf16*  hbuf    = (bf16*) (ws + 33554432);        // 67108864 B
  bf16*  qkv_wb  = (bf16*) (ws + 100663296);       //   393216 B
  bf16*  proj_wb = (bf16*) (ws + 101056512);       //   131072 B
  bf16*  fc1_wb  = (bf16*) (ws + 101187584);       //   524288 B
  bf16*  fc2_wb  = (bf16*) (ws + 101711872);       //   524288 B
  float* bias_g  = (float*)(ws + 102236160);       //   131072 B  (total ~97.6 MB)

  prep_weights<<<1024, 256, 0, stream>>>(qkv_w, proj_w, fc1_w, fc2_w,
                                         qkv_wb, proj_wb, fc1_wb, fc2_wb);
  prep_bias<<<1, 256, 0, stream>>>(cpb_w1, cpb_b1, cpb_w2, bias_g);
  k_attn<<<512, 256, 0, stream>>>(x, qkv_wb, qkv_b, nq_w, nk_w,
                                  proj_wb, proj_b, n1w, n1b, bias_g, x1);
  k_fc1<<<dim3(512, 4), 256, 0, stream>>>(x1, fc1_wb, fc1_b, hbuf);
  k_fc2<<<512, 256, 0, stream>>>(x1, hbuf, fc2_wb, fc2_b, n2w, n2b, (float*)d_out);
}

// Round 2
// 274.682 us; speedup vs baseline: 1.6595x; 1.6595x over previous
//
#include <hip/hip_runtime.h>
#include <hip/hip_bf16.h>
#include <math.h>

typedef __bf16 bf16;
typedef bf16  bf16x8 __attribute__((ext_vector_type(8)));
typedef float f32x4  __attribute__((ext_vector_type(4)));

#define MFMA16(a,b,c) __builtin_amdgcn_mfma_f32_16x16x32_bf16(a,b,c,0,0,0)
#define LDS_FENCE() asm volatile("s_waitcnt lgkmcnt(0)" ::: "memory")

__device__ __forceinline__ bf16x8 cvt8(const float4& a, const float4& b) {
  bf16x8 v;
  v[0]=(bf16)a.x; v[1]=(bf16)a.y; v[2]=(bf16)a.z; v[3]=(bf16)a.w;
  v[4]=(bf16)b.x; v[5]=(bf16)b.y; v[6]=(bf16)b.z; v[7]=(bf16)b.w;
  return v;
}

// ---------------- prep: fp32 weights -> bf16 ----------------
__global__ void prep_weights(const float* __restrict__ qkv_w, const float* __restrict__ proj_w,
                             const float* __restrict__ fc1_w, const float* __restrict__ fc2_w,
                             bf16* __restrict__ qkv_wb, bf16* __restrict__ proj_wb,
                             bf16* __restrict__ fc1_wb, bf16* __restrict__ fc2_wb) {
  int i = blockIdx.x * 256 + threadIdx.x;
  if (i < 196608) qkv_wb[i] = (bf16)qkv_w[i];
  if (i <  65536) proj_wb[i] = (bf16)proj_w[i];
  if (i < 262144) { fc1_wb[i] = (bf16)fc1_w[i]; fc2_wb[i] = (bf16)fc2_w[i]; }
}

// ---------------- prep: CPB MLP -> tab[225][8] ----------------
__global__ void prep_tab(const float* __restrict__ w1, const float* __restrict__ b1,
                         const float* __restrict__ w2, float* __restrict__ tab_g) {
  const int c = blockIdx.x;           // 225 coord pairs
  const int a = c / 15, bq = c % 15;
  const float g0 = (float)(a - 7) * (8.0f / 7.0f);
  const float g1 = (float)(bq - 7) * (8.0f / 7.0f);
  const float t0 = copysignf(log2f(fabsf(g0) + 1.0f) * (1.0f/3.0f), g0);
  const float t1 = copysignf(log2f(fabsf(g1) + 1.0f) * (1.0f/3.0f), g1);
  const int lane = threadIdx.x;       // 64 threads, 8 hidden each
  float acc[8] = {0.f,0.f,0.f,0.f,0.f,0.f,0.f,0.f};
#pragma unroll
  for (int e = 0; e < 8; ++e) {
    const int h = lane*8 + e;
    float hv = t0 * w1[h*3 + 0] + t1 * w1[h*3 + 1] + b1[h];
    hv = fmaxf(hv, 0.0f);
#pragma unroll
    for (int j = 0; j < 8; ++j) acc[j] += hv * w2[j*512 + h];
  }
#pragma unroll
  for (int j = 0; j < 8; ++j) {
    acc[j] += __shfl_xor(acc[j], 1);
    acc[j] += __shfl_xor(acc[j], 2);
    acc[j] += __shfl_xor(acc[j], 4);
    acc[j] += __shfl_xor(acc[j], 8);
    acc[j] += __shfl_xor(acc[j], 16);
    acc[j] += __shfl_xor(acc[j], 32);
  }
  if (lane == 0) {
#pragma unroll
    for (int j = 0; j < 8; ++j) tab_g[c*8 + j] = acc[j];
  }
}

// ---------------- prep: expand tab -> bias[8][64][64] with sigmoid ----------------
__global__ void prep_expand(const float* __restrict__ tab_g, float* __restrict__ bias_g) {
  const int idx = blockIdx.x * 256 + threadIdx.x;   // 32768
  const int head = idx >> 12, i = (idx >> 6) & 63, j = idx & 63;
  const int dy = (i >> 3) - (j >> 3), dx = (i & 7) - (j & 7);
  const float v = tab_g[((dy + 7)*15 + (dx + 7))*8 + head];
  bias_g[idx] = 16.0f / (1.0f + expf(-v));
}

// ---------------- fused window attention + proj + LN1 + shortcut ----------------
// one block per (batch, window); 8 waves (512 threads).
__launch_bounds__(512, 2)
__global__ void k_attn(const float* __restrict__ x,
                       const bf16* __restrict__ qkv_wb, const float* __restrict__ qkv_b,
                       const float* __restrict__ nq_w, const float* __restrict__ nk_w,
                       const bf16* __restrict__ proj_wb, const float* __restrict__ proj_b,
                       const float* __restrict__ n1w, const float* __restrict__ n1b,
                       const float* __restrict__ bias_g,
                       float* __restrict__ x1) {
  __shared__ __align__(16) unsigned char SM[132096];
  const int tid  = threadIdx.x;
  const int wv   = tid >> 6;          // 0..7
  const int lane = tid & 63;
  const int lm   = lane & 15;
  const int lg   = lane >> 4;
  const int lk   = lg << 3;
  const int blk  = blockIdx.x;
  const int b    = blk >> 6;
  const int win  = blk & 63;
  const int wy   = win >> 3, wx = win & 7;

  const int QA = 32768;   // q [64][256] bf16 swizzled; later y_all
  const int KA = 65536;   // k [64][256] bf16
  const int VT = 98304;   // v^T [8 heads][32 d][64 t] bf16, swizzle keyed on d
  const int Y2 = 65536;   // proj epilogue fp32 [64][260] padded (overlays KA+VT, dead by then)

  // ---- stage shifted-window x tile -> bf16 LDS [64][256], XOR-swizzled
  {
    const int t = tid >> 3, q = tid & 7;
    const int iy = t >> 3, ix = t & 7;
    const int gh = (wy*8 + iy + 4) & 63, gw = (wx*8 + ix + 4) & 63;
    const float* src = x + (size_t)(b*4096 + gh*64 + gw) * 256 + q*32;
#pragma unroll
    for (int i = 0; i < 4; ++i) {
      float4 f0 = *(const float4*)(src + i*8);
      float4 f1 = *(const float4*)(src + i*8 + 4);
      *(bf16x8*)(SM + ((t*512 + (q*32 + i*8)*2) ^ ((t&7)<<4))) = cvt8(f0, f1);
    }
  }
  __syncthreads();

  // ---- QKV GEMM: wave covers 96 of 768 cols
  {
    f32x4 acc[4][6] = {};
#pragma unroll
    for (int kk = 0; kk < 8; ++kk) {
      const int ko = kk*32 + lk;
      bf16x8 a[4], bb[6];
#pragma unroll
      for (int m = 0; m < 4; ++m) {
        const int t = m*16 + lm;
        a[m] = *(const bf16x8*)(SM + ((t*512 + ko*2) ^ ((t&7)<<4)));
      }
#pragma unroll
      for (int n = 0; n < 6; ++n) {
        const int j = wv*96 + n*16 + lm;
        bb[n] = *(const bf16x8*)(qkv_wb + j*256 + ko);
      }
#pragma unroll
      for (int m = 0; m < 4; ++m)
#pragma unroll
        for (int n = 0; n < 6; ++n)
          acc[m][n] = MFMA16(a[m], bb[n], acc[m][n]);
    }
#pragma unroll
    for (int n = 0; n < 6; ++n) {
      const int jf = wv*96 + n*16;     // frag base (16-aligned, uniform channel)
      const int j  = jf + lm;
      const float bj = qkv_b[j];
#pragma unroll
      for (int m = 0; m < 4; ++m)
#pragma unroll
        for (int r = 0; r < 4; ++r) {
          const int t = m*16 + lg*4 + r;
          const float v = acc[m][n][r] + bj;
          if (jf < 256) {
            *(bf16*)(SM + QA + ((t*512 + j*2) ^ ((t&7)<<4))) = (bf16)v;
          } else if (jf < 512) {
            const int jj = j - 256;
            *(bf16*)(SM + KA + ((t*512 + jj*2) ^ ((t&7)<<4))) = (bf16)v;
          } else {
            const int jj = j - 512;
            const int hh = jj >> 5, d = jj & 31;
            *(bf16*)(SM + VT + hh*4096 + ((d*128 + t*2) ^ ((d&7)<<4))) = (bf16)v;
          }
        }
    }
  }
  __syncthreads();

  // ---- per-(token,head) RMSNorm on q and k (1024 jobs / 512 threads)
#pragma unroll 1
  for (int p = tid; p < 1024; p += 512) {
    const int isk = p >> 9;
    const int pp  = p & 511;
    const int t = pp >> 3, hh = pp & 7;
    const int base = isk ? KA : QA;
    const float* nw = isk ? nk_w : nq_w;
    bf16x8 vv[4];
    float ssq = 0.f;
#pragma unroll
    for (int c = 0; c < 4; ++c) {
      vv[c] = *(const bf16x8*)(SM + base + ((t*512 + (hh*32 + c*8)*2) ^ ((t&7)<<4)));
#pragma unroll
      for (int e = 0; e < 8; ++e) { const float f = (float)vv[c][e]; ssq += f*f; }
    }
    const float sc = rsqrtf(ssq * (1.0f/32.0f) + 1.1920929e-07f);
#pragma unroll
    for (int c = 0; c < 4; ++c) {
      bf16x8 o;
#pragma unroll
      for (int e = 0; e < 8; ++e) o[e] = (bf16)((float)vv[c][e] * sc * nw[c*8 + e]);
      *(bf16x8*)(SM + base + ((t*512 + (hh*32 + c*8)*2) ^ ((t&7)<<4))) = o;
    }
  }
  __syncthreads();

  // ---- attention: wave wv handles head h = wv
  f32x4 yacc[4][2];
  {
    const int h  = wv;
    const int PB = wv * 4096;   // wave-private P half-buffer [32][64] bf16 in dead x area
    bf16x8 qf[4], kf[4];
#pragma unroll
    for (int m = 0; m < 4; ++m)
      qf[m] = *(const bf16x8*)(SM + QA + (((m*16+lm)*512 + (h*32+lk)*2) ^ ((lm&7)<<4)));
#pragma unroll
    for (int n = 0; n < 4; ++n)
      kf[n] = *(const bf16x8*)(SM + KA + (((n*16+lm)*512 + (h*32+lk)*2) ^ ((lm&7)<<4)));
    f32x4 s[4][4];
#pragma unroll
    for (int m = 0; m < 4; ++m)
#pragma unroll
      for (int n = 0; n < 4; ++n) {
        f32x4 z = {};
        s[m][n] = MFMA16(qf[m], kf[n], z);
      }
    // bias + shift mask
#pragma unroll
    for (int n = 0; n < 4; ++n) {
      const int ct = n*16 + lm;
      const int idc = ((wy==7) ? (((ct>>3) < 4) ? 1 : 2) : 0) * 3
                    + ((wx==7) ? (((ct&7)  < 4) ? 1 : 2) : 0);
#pragma unroll
      for (int m = 0; m < 4; ++m)
#pragma unroll
        for (int r = 0; r < 4; ++r) {
          const int rt = m*16 + lg*4 + r;
          const int idr = ((wy==7) ? (((rt>>3) < 4) ? 1 : 2) : 0) * 3
                        + ((wx==7) ? (((rt&7)  < 4) ? 1 : 2) : 0);
          float add = bias_g[h*4096 + rt*64 + ct];
          if (idr != idc) add -= 100.0f;
          s[m][n][r] += add;
        }
    }
    // row softmax
#pragma unroll
    for (int m = 0; m < 4; ++m)
#pragma unroll
      for (int r = 0; r < 4; ++r) {
        float v0 = s[m][0][r], v1 = s[m][1][r], v2 = s[m][2][r], v3 = s[m][3][r];
        float mx = fmaxf(fmaxf(v0, v1), fmaxf(v2, v3));
        mx = fmaxf(mx, __shfl_xor(mx, 1));
        mx = fmaxf(mx, __shfl_xor(mx, 2));
        mx = fmaxf(mx, __shfl_xor(mx, 4));
        mx = fmaxf(mx, __shfl_xor(mx, 8));
        v0 = expf(v0 - mx); v1 = expf(v1 - mx); v2 = expf(v2 - mx); v3 = expf(v3 - mx);
        float sm = v0 + v1 + v2 + v3;
        sm += __shfl_xor(sm, 1);
        sm += __shfl_xor(sm, 2);
        sm += __shfl_xor(sm, 4);
        sm += __shfl_xor(sm, 8);
        const float inv = 1.0f / sm;
        s[m][0][r] = v0*inv; s[m][1][r] = v1*inv; s[m][2][r] = v2*inv; s[m][3][r] = v3*inv;
      }
#pragma unroll
    for (int m = 0; m < 4; ++m)
#pragma unroll
      for (int nf = 0; nf < 2; ++nf) { f32x4 z = {}; yacc[m][nf] = z; }
    // PV in two 32-row halves through the 4KB wave-private strip
#pragma unroll
    for (int mh = 0; mh < 2; ++mh) {
      LDS_FENCE();   // prior half's reads drained before overwrite
#pragma unroll
      for (int ml = 0; ml < 2; ++ml)
#pragma unroll
        for (int n = 0; n < 4; ++n)
#pragma unroll
          for (int r = 0; r < 4; ++r) {
            const int rl = ml*16 + lg*4 + r, ct = n*16 + lm;
            *(bf16*)(SM + PB + ((rl*128 + ct*2) ^ ((rl&7)<<4))) = (bf16)s[mh*2+ml][n][r];
          }
      LDS_FENCE();   // writes visible before reads
#pragma unroll
      for (int ks = 0; ks < 2; ++ks) {
        bf16x8 pa[2], vb[2];
#pragma unroll
        for (int ml = 0; ml < 2; ++ml) {
          const int rl = ml*16 + lm;
          pa[ml] = *(const bf16x8*)(SM + PB + ((rl*128 + (ks*32+lk)*2) ^ ((rl&7)<<4)));
        }
#pragma unroll
        for (int nf = 0; nf < 2; ++nf) {
          const int d = nf*16 + lm;
          vb[nf] = *(const bf16x8*)(SM + VT + h*4096 + ((d*128 + (ks*32+lk)*2) ^ ((d&7)<<4)));
        }
#pragma unroll
        for (int ml = 0; ml < 2; ++ml)
#pragma unroll
          for (int nf = 0; nf < 2; ++nf)
            yacc[mh*2+ml][nf] = MFMA16(pa[ml], vb[nf], yacc[mh*2+ml][nf]);
      }
    }
    // y (head h) -> QA cols h*32..h*32+32 (own wave's q cols, already consumed)
#pragma unroll
    for (int m = 0; m < 4; ++m)
#pragma unroll
      for (int nf = 0; nf < 2; ++nf)
#pragma unroll
        for (int r = 0; r < 4; ++r) {
          const int t = m*16 + lg*4 + r;
          const int c = h*32 + nf*16 + lm;
          *(bf16*)(SM + QA + ((t*512 + c*2) ^ ((t&7)<<4))) = (bf16)yacc[m][nf][r];
        }
  }
  __syncthreads();

  // ---- proj: wave covers 32 cols, K=256
  {
    f32x4 acc[4][2] = {};
#pragma unroll
    for (int kk = 0; kk < 8; ++kk) {
      const int ko = kk*32 + lk;
      bf16x8 a[4], bb[2];
#pragma unroll
      for (int m = 0; m < 4; ++m) {
        const int t = m*16 + lm;
        a[m] = *(const bf16x8*)(SM + QA + ((t*512 + ko*2) ^ ((t&7)<<4)));
      }
#pragma unroll
      for (int n = 0; n < 2; ++n) {
        const int j = wv*32 + n*16 + lm;
        bb[n] = *(const bf16x8*)(proj_wb + j*256 + ko);
      }
#pragma unroll
      for (int m = 0; m < 4; ++m)
#pragma unroll
        for (int n = 0; n < 2; ++n)
          acc[m][n] = MFMA16(a[m], bb[n], acc[m][n]);
    }
#pragma unroll
    for (int n = 0; n < 2; ++n) {
      const int j = wv*32 + n*16 + lm;
      const float bj = proj_b[j];
#pragma unroll
      for (int m = 0; m < 4; ++m)
#pragma unroll
        for (int r = 0; r < 4; ++r) {
          const int t = m*16 + lg*4 + r;
          *(float*)(SM + Y2 + t*1040 + j*4) = acc[m][n][r] + bj;   // padded: 260 f/row
        }
    }
  }
  __syncthreads();

  // ---- LN(norm1) + shortcut, scatter to x1 at unshifted position (8 thr/row)
  {
    const int t = tid >> 3, sub = tid & 7;
    const float* row = (const float*)(SM + Y2 + t*1040) + sub*32;
    float sum = 0.f, ssq = 0.f;
#pragma unroll
    for (int i = 0; i < 8; ++i) {
      float4 f = *(const float4*)(row + i*4);
      sum += f.x + f.y + f.z + f.w;
      ssq += f.x*f.x + f.y*f.y + f.z*f.z + f.w*f.w;
    }
    sum += __shfl_xor(sum, 1); sum += __shfl_xor(sum, 2); sum += __shfl_xor(sum, 4);
    ssq += __shfl_xor(ssq, 1); ssq += __shfl_xor(ssq, 2); ssq += __shfl_xor(ssq, 4);
    const float mu  = sum * (1.0f/256.0f);
    const float var = ssq * (1.0f/256.0f) - mu*mu;
    const float inv = rsqrtf(var + 1e-5f);
    const int iy = t >> 3, ix = t & 7;
    const int gh = (wy*8 + iy + 4) & 63, gw = (wx*8 + ix + 4) & 63;
    const size_t grow = (size_t)(b*4096 + gh*64 + gw) * 256;
#pragma unroll
    for (int i = 0; i < 8; ++i) {
      float4 f = *(const float4*)(row + i*4);
      const int c = sub*32 + i*4;
      float4 o;
      o.x = (f.x - mu)*inv*n1w[c+0] + n1b[c+0] + x[grow + c + 0];
      o.y = (f.y - mu)*inv*n1w[c+1] + n1b[c+1] + x[grow + c + 1];
      o.z = (f.z - mu)*inv*n1w[c+2] + n1b[c+2] + x[grow + c + 2];
      o.w = (f.w - mu)*inv*n1w[c+3] + n1b[c+3] + x[grow + c + 3];
      *(float4*)(x1 + grow + c) = o;
    }
  }
}

// ---------------- fc1 + exact GELU -> h (bf16); 512 thr, 2 blocks/CU ----------------
__launch_bounds__(512, 4)
__global__ void k_fc1(const float* __restrict__ x1, const bf16* __restrict__ fc1_wb,
                      const float* __restrict__ fc1_b, bf16* __restrict__ h) {
  __shared__ __align__(16) unsigned char SM[65536];   // XA 0..32K, OST 32K..64K
  const int tid = threadIdx.x;
  const int wv = tid >> 6, lane = tid & 63;
  const int lm = lane & 15, lg = lane >> 4, lk = lg << 3;
  const int mb = blockIdx.x, nb = blockIdx.y;
  {
    const int t = tid >> 3, q = tid & 7;
    const float* src = x1 + (size_t)(mb*64 + t) * 256 + q*32;
#pragma unroll
    for (int i = 0; i < 4; ++i) {
      float4 f0 = *(const float4*)(src + i*8);
      float4 f1 = *(const float4*)(src + i*8 + 4);
      *(bf16x8*)(SM + ((t*512 + (q*32 + i*8)*2) ^ ((t&7)<<4))) = cvt8(f0, f1);
    }
  }
  __syncthreads();
  f32x4 acc[4][4] = {};
#pragma unroll
  for (int kk = 0; kk < 8; ++kk) {
    const int ko = kk*32 + lk;
    bf16x8 a[4], bb[4];
#pragma unroll
    for (int m = 0; m < 4; ++m) {
      const int t = m*16 + lm;
      a[m] = *(const bf16x8*)(SM + ((t*512 + ko*2) ^ ((t&7)<<4)));
    }
#pragma unroll
    for (int n = 0; n < 4; ++n) {
      const int j = nb*512 + wv*64 + n*16 + lm;
      bb[n] = *(const bf16x8*)(fc1_wb + (size_t)j*256 + ko);
    }
#pragma unroll
    for (int m = 0; m < 4; ++m)
#pragma unroll
      for (int n = 0; n < 4; ++n)
        acc[m][n] = MFMA16(a[m], bb[n], acc[m][n]);
  }
  // output in two 256-col chunks through OST
#pragma unroll 1
  for (int oc = 0; oc < 2; ++oc) {
    __syncthreads();
    if ((wv >> 2) == oc) {
#pragma unroll
      for (int n = 0; n < 4; ++n) {
        const int jj = (wv&3)*64 + n*16 + lm;
        const float bj = fc1_b[nb*512 + oc*256 + jj];
#pragma unroll
        for (int m = 0; m < 4; ++m)
#pragma unroll
          for (int r = 0; r < 4; ++r) {
            const int t = m*16 + lg*4 + r;
            float v = acc[m][n][r] + bj;
            v = 0.5f * v * (1.0f + erff(v * 0.70710678118654752f));
            *(bf16*)(SM + 32768 + ((t*512 + jj*2) ^ ((t&7)<<4))) = (bf16)v;
          }
      }
    }
    __syncthreads();
    {
      const int t = tid >> 3, sub = tid & 7;
      bf16* dst = h + (size_t)(mb*64 + t) * 1024 + nb*512 + oc*256 + sub*32;
#pragma unroll
      for (int i = 0; i < 4; ++i) {
        bf16x8 v = *(const bf16x8*)(SM + 32768 + ((t*512 + (sub*32 + i*8)*2) ^ ((t&7)<<4)));
        *(bf16x8*)(dst + i*8) = v;
      }
    }
  }
}

// ---------------- fc2 + LN(norm2) + residual -> out; 512 thr ----------------
__launch_bounds__(512, 2)
__global__ void k_fc2(const float* __restrict__ x1, const bf16* __restrict__ h,
                      const bf16* __restrict__ fc2_wb, const float* __restrict__ fc2_b,
                      const float* __restrict__ n2w, const float* __restrict__ n2b,
                      float* __restrict__ out) {
  __shared__ __align__(16) unsigned char SM[99328];   // HS 32K + y2 padded 66.5K
  const int tid = threadIdx.x;
  const int wv = tid >> 6, lane = tid & 63;
  const int lm = lane & 15, lg = lane >> 4, lk = lg << 3;
  const int mb = blockIdx.x;
  const int t8 = tid >> 3, sub = tid & 7;
  const bf16* hrow = h + (size_t)(mb*64 + t8) * 1024 + sub*32;
  bf16x8 v[4];
#pragma unroll
  for (int i = 0; i < 4; ++i) v[i] = *(const bf16x8*)(hrow + i*8);
  f32x4 acc[4][2] = {};
#pragma unroll 1
  for (int kc = 0; kc < 4; ++kc) {
#pragma unroll
    for (int i = 0; i < 4; ++i)
      *(bf16x8*)(SM + ((t8*512 + (sub*32 + i*8)*2) ^ ((t8&7)<<4))) = v[i];
    __syncthreads();
    if (kc < 3) {
#pragma unroll
      for (int i = 0; i < 4; ++i) v[i] = *(const bf16x8*)(hrow + (kc+1)*256 + i*8);
    }
#pragma unroll
    for (int kk = 0; kk < 8; ++kk) {
      const int ko = kk*32 + lk;
      bf16x8 a[4], bb[2];
#pragma unroll
      for (int m = 0; m < 4; ++m) {
        const int t = m*16 + lm;
        a[m] = *(const bf16x8*)(SM + ((t*512 + ko*2) ^ ((t&7)<<4)));
      }
#pragma unroll
      for (int n = 0; n < 2; ++n) {
        const int j = wv*32 + n*16 + lm;
        bb[n] = *(const bf16x8*)(fc2_wb + (size_t)j*1024 + kc*256 + ko);
      }
#pragma unroll
      for (int m = 0; m < 4; ++m)
#pragma unroll
        for (int n = 0; n < 2; ++n)
          acc[m][n] = MFMA16(a[m], bb[n], acc[m][n]);
    }
    __syncthreads();
  }
#pragma unroll
  for (int n = 0; n < 2; ++n) {
    const int j = wv*32 + n*16 + lm;
    const float bj = fc2_b[j];
#pragma unroll
    for (int m = 0; m < 4; ++m)
#pragma unroll
      for (int r = 0; r < 4; ++r) {
        const int t = m*16 + lg*4 + r;
        *(float*)(SM + 32768 + t*1040 + j*4) = acc[m][n][r] + bj;
      }
  }
  __syncthreads();
  {
    const float* row = (const float*)(SM + 32768 + t8*1040) + sub*32;
    float sum = 0.f, ssq = 0.f;
#pragma unroll
    for (int i = 0; i < 8; ++i) {
      float4 f = *(const float4*)(row + i*4);
      sum += f.x + f.y + f.z + f.w;
      ssq += f.x*f.x + f.y*f.y + f.z*f.z + f.w*f.w;
    }
    sum += __shfl_xor(sum, 1); sum += __shfl_xor(sum, 2); sum += __shfl_xor(sum, 4);
    ssq += __shfl_xor(ssq, 1); ssq += __shfl_xor(ssq, 2); ssq += __shfl_xor(ssq, 4);
    const float mu  = sum * (1.0f/256.0f);
    const float var = ssq * (1.0f/256.0f) - mu*mu;
    const float inv = rsqrtf(var + 1e-5f);
    const size_t grow = (size_t)(mb*64 + t8) * 256;
#pragma unroll
    for (int i = 0; i < 8; ++i) {
      float4 f = *(const float4*)(row + i*4);
      const int c = sub*32 + i*4;
      float4 o;
      o.x = (f.x - mu)*inv*n2w[c+0] + n2b[c+0] + x1[grow + c + 0];
      o.y = (f.y - mu)*inv*n2w[c+1] + n2b[c+1] + x1[grow + c + 1];
      o.z = (f.z - mu)*inv*n2w[c+2] + n2b[c+2] + x1[grow + c + 2];
      o.w = (f.w - mu)*inv*n2w[c+3] + n2b[c+3] + x1[grow + c + 3];
      *(float4*)(out + grow + c) = o;
    }
  }
}

extern "C" void kernel_launch(void* const* d_in, const int* in_sizes, int n_in,
                              void* d_out, int out_size, void* d_ws, size_t ws_size,
                              hipStream_t stream) {
  const float* x      = (const float*)d_in[0];
  const float* qkv_w  = (const float*)d_in[1];
  const float* qkv_b  = (const float*)d_in[2];
  const float* nq_w   = (const float*)d_in[3];
  const float* nk_w   = (const float*)d_in[4];
  const float* cpb_w1 = (const float*)d_in[5];
  const float* cpb_b1 = (const float*)d_in[6];
  const float* cpb_w2 = (const float*)d_in[7];
  const float* proj_w = (const float*)d_in[8];
  const float* proj_b = (const float*)d_in[9];
  const float* n1w    = (const float*)d_in[10];
  const float* n1b    = (const float*)d_in[11];
  const float* fc1_w  = (const float*)d_in[12];
  const float* fc1_b  = (const float*)d_in[13];
  const float* fc2_w  = (const float*)d_in[14];
  const float* fc2_b  = (const float*)d_in[15];
  const float* n2w    = (const float*)d_in[16];
  const float* n2b    = (const float*)d_in[17];

  char* ws = (char*)d_ws;
  float* x1      = (float*)(ws);                   // 33554432 B
  bf16*  hbuf    = (bf16*) (ws + 33554432);        // 67108864 B
  bf16*  qkv_wb  = (bf16*) (ws + 100663296);       //   393216 B
  bf16*  proj_wb = (bf16*) (ws + 101056512);       //   131072 B
  bf16*  fc1_wb  = (bf16*) (ws + 101187584);       //   524288 B
  bf16*  fc2_wb  = (bf16*) (ws + 101711872);       //   524288 B
  float* bias_g  = (float*)(ws + 102236160);       //   131072 B
  float* tab_g   = (float*)(ws + 102367232);       //     7200 B

  prep_weights<<<1024, 256, 0, stream>>>(qkv_w, proj_w, fc1_w, fc2_w,
                                         qkv_wb, proj_wb, fc1_wb, fc2_wb);
  prep_tab<<<225, 64, 0, stream>>>(cpb_w1, cpb_b1, cpb_w2, tab_g);
  prep_expand<<<128, 256, 0, stream>>>(tab_g, bias_g);
  k_attn<<<512, 512, 0, stream>>>(x, qkv_wb, qkv_b, nq_w, nk_w,
                                  proj_wb, proj_b, n1w, n1b, bias_g, x1);
  k_fc1<<<dim3(512, 2), 512, 0, stream>>>(x1, fc1_wb, fc1_b, hbuf);
  k_fc2<<<512, 512, 0, stream>>>(x1, hbuf, fc2_wb, fc2_b, n2w, n2b, (float*)d_out);
}

// Round 4
// 236.722 us; speedup vs baseline: 1.9256x; 1.1604x over previous
//
#include <hip/hip_runtime.h>
#include <hip/hip_bf16.h>
#include <math.h>

typedef __bf16 bf16;
typedef bf16  bf16x8 __attribute__((ext_vector_type(8)));
typedef float f32x4  __attribute__((ext_vector_type(4)));

#define MFMA16(a,b,c) __builtin_amdgcn_mfma_f32_16x16x32_bf16(a,b,c,0,0,0)
#define FENCE() do { asm volatile("s_waitcnt lgkmcnt(0)" ::: "memory"); __builtin_amdgcn_sched_barrier(0); } while(0)

__device__ __forceinline__ bf16x8 cvt8(const float4& a, const float4& b) {
  bf16x8 v;
  v[0]=(bf16)a.x; v[1]=(bf16)a.y; v[2]=(bf16)a.z; v[3]=(bf16)a.w;
  v[4]=(bf16)b.x; v[5]=(bf16)b.y; v[6]=(bf16)b.z; v[7]=(bf16)b.w;
  return v;
}

// ---------------- prep: fp32 weights -> bf16 ----------------
__global__ void prep_weights(const float* __restrict__ qkv_w, const float* __restrict__ proj_w,
                             const float* __restrict__ fc1_w, const float* __restrict__ fc2_w,
                             bf16* __restrict__ qkv_wb, bf16* __restrict__ proj_wb,
                             bf16* __restrict__ fc1_wb, bf16* __restrict__ fc2_wb) {
  int i = blockIdx.x * 256 + threadIdx.x;
  if (i < 196608) qkv_wb[i] = (bf16)qkv_w[i];
  if (i <  65536) proj_wb[i] = (bf16)proj_w[i];
  if (i < 262144) { fc1_wb[i] = (bf16)fc1_w[i]; fc2_wb[i] = (bf16)fc2_w[i]; }
}

// ---------------- prep: CPB MLP -> tab[225][8] ----------------
__global__ void prep_tab(const float* __restrict__ w1, const float* __restrict__ b1,
                         const float* __restrict__ w2, float* __restrict__ tab_g) {
  const int c = blockIdx.x;           // 225 coord pairs
  const int a = c / 15, bq = c % 15;
  const float g0 = (float)(a - 7) * (8.0f / 7.0f);
  const float g1 = (float)(bq - 7) * (8.0f / 7.0f);
  const float t0 = copysignf(log2f(fabsf(g0) + 1.0f) * (1.0f/3.0f), g0);
  const float t1 = copysignf(log2f(fabsf(g1) + 1.0f) * (1.0f/3.0f), g1);
  const int lane = threadIdx.x;       // 64 threads, 8 hidden each
  float acc[8] = {0.f,0.f,0.f,0.f,0.f,0.f,0.f,0.f};
#pragma unroll
  for (int e = 0; e < 8; ++e) {
    const int h = lane*8 + e;
    float hv = t0 * w1[h*3 + 0] + t1 * w1[h*3 + 1] + b1[h];
    hv = fmaxf(hv, 0.0f);
#pragma unroll
    for (int j = 0; j < 8; ++j) acc[j] += hv * w2[j*512 + h];
  }
#pragma unroll
  for (int j = 0; j < 8; ++j) {
    acc[j] += __shfl_xor(acc[j], 1);
    acc[j] += __shfl_xor(acc[j], 2);
    acc[j] += __shfl_xor(acc[j], 4);
    acc[j] += __shfl_xor(acc[j], 8);
    acc[j] += __shfl_xor(acc[j], 16);
    acc[j] += __shfl_xor(acc[j], 32);
  }
  if (lane == 0) {
#pragma unroll
    for (int j = 0; j < 8; ++j) tab_g[c*8 + j] = acc[j];
  }
}

// ---------------- prep: expand tab -> bias_t[8][ct=64][rt=64] (TRANSPOSED) ----------------
__global__ void prep_expand(const float* __restrict__ tab_g, float* __restrict__ bias_t) {
  const int idx = blockIdx.x * 256 + threadIdx.x;   // 32768
  const int head = idx >> 12, ct = (idx >> 6) & 63, rt = idx & 63;
  const int dy = (rt >> 3) - (ct >> 3), dx = (rt & 7) - (ct & 7);
  const float v = tab_g[((dy + 7)*15 + (dx + 7))*8 + head];
  bias_t[idx] = 16.0f / (1.0f + expf(-v));
}

// ---------------- fused window attention + proj + LN1 + shortcut ----------------
// one block per (batch, window); 8 waves; wave = head. LDS 64KB -> 2 blocks/CU.
__launch_bounds__(512, 4)
__global__ void k_attn(const float* __restrict__ x,
                       const bf16* __restrict__ qkv_wb, const float* __restrict__ qkv_b,
                       const float* __restrict__ nq_w, const float* __restrict__ nk_w,
                       const bf16* __restrict__ proj_wb, const float* __restrict__ proj_b,
                       const float* __restrict__ n1w, const float* __restrict__ n1b,
                       const float* __restrict__ bias_t,
                       float* __restrict__ x1) {
  __shared__ __align__(16) unsigned char SM[65536];
  const int tid  = threadIdx.x;
  const int wv   = tid >> 6;          // 0..7 == head
  const int lane = tid & 63;
  const int lm   = lane & 15;
  const int lg   = lane >> 4;
  const int lk   = lg << 3;
  const int blk  = blockIdx.x;
  const int b    = blk >> 6;
  const int win  = blk & 63;
  const int wy   = win >> 3, wx = win & 7;
  const int h    = wv;
  const int SB   = 32768 + wv*4096;   // wave-private 4KB bounce strip

  // ---- stage shifted-window x tile -> bf16 LDS [64][256], XOR-swizzled (XA = 0..32K)
  {
    const int t = tid >> 3, q8 = tid & 7;
    const int iy = t >> 3, ix = t & 7;
    const int gh = (wy*8 + iy + 4) & 63, gw = (wx*8 + ix + 4) & 63;
    const float* src = x + (size_t)(b*4096 + gh*64 + gw) * 256 + q8*32;
#pragma unroll
    for (int i = 0; i < 4; ++i) {
      float4 f0 = *(const float4*)(src + i*8);
      float4 f1 = *(const float4*)(src + i*8 + 4);
      *(bf16x8*)(SM + ((t*512 + (q8*32 + i*8)*2) ^ ((t&7)<<4))) = cvt8(f0, f1);
    }
  }
  __syncthreads();   // B0

  bf16x8 qf[4], kf[4], vb[2][2];

  // ---- QKV pass0: q (d 0..32) + k (d 0..32) for this head
  {
    const int jq[4] = { h*32 + lm, h*32 + 16 + lm, 256 + h*32 + lm, 256 + h*32 + 16 + lm };
    f32x4 acc[4][4] = {};
#pragma unroll
    for (int kk = 0; kk < 8; ++kk) {
      const int ko = kk*32 + lk;
      bf16x8 a[4], bb[4];
#pragma unroll
      for (int m = 0; m < 4; ++m) {
        const int t = m*16 + lm;
        a[m] = *(const bf16x8*)(SM + ((t*512 + ko*2) ^ ((t&7)<<4)));
      }
#pragma unroll
      for (int n = 0; n < 4; ++n)
        bb[n] = *(const bf16x8*)(qkv_wb + jq[n]*256 + ko);
#pragma unroll
      for (int m = 0; m < 4; ++m)
#pragma unroll
        for (int n = 0; n < 4; ++n)
          acc[m][n] = MFMA16(a[m], bb[n], acc[m][n]);
    }
    // bias
    float bj[4];
#pragma unroll
    for (int n = 0; n < 4; ++n) bj[n] = qkv_b[jq[n]];
#pragma unroll
    for (int m = 0; m < 4; ++m)
#pragma unroll
      for (int n = 0; n < 4; ++n)
#pragma unroll
        for (int r = 0; r < 4; ++r) acc[m][n][r] += bj[n];
    // in-register RMSNorm (q: n=0,1 ; k: n=2,3)
    const float nqw0 = nq_w[lm], nqw1 = nq_w[16+lm];
    const float nkw0 = nk_w[lm], nkw1 = nk_w[16+lm];
#pragma unroll
    for (int m = 0; m < 4; ++m)
#pragma unroll
      for (int r = 0; r < 4; ++r) {
        float q0 = acc[m][0][r], q1 = acc[m][1][r];
        float k0 = acc[m][2][r], k1 = acc[m][3][r];
        float sq = q0*q0 + q1*q1, sk = k0*k0 + k1*k1;
        sq += __shfl_xor(sq, 1); sk += __shfl_xor(sk, 1);
        sq += __shfl_xor(sq, 2); sk += __shfl_xor(sk, 2);
        sq += __shfl_xor(sq, 4); sk += __shfl_xor(sk, 4);
        sq += __shfl_xor(sq, 8); sk += __shfl_xor(sk, 8);
        const float scq = rsqrtf(sq * (1.0f/32.0f) + 1.1920929e-07f);
        const float sck = rsqrtf(sk * (1.0f/32.0f) + 1.1920929e-07f);
        acc[m][0][r] = q0*scq*nqw0; acc[m][1][r] = q1*scq*nqw1;
        acc[m][2][r] = k0*sck*nkw0; acc[m][3][r] = k1*sck*nkw1;
      }
    // bounce q through strip (frag-linear layout), then k
#pragma unroll
    for (int m = 0; m < 4; ++m)
#pragma unroll
      for (int n = 0; n < 2; ++n)
#pragma unroll
        for (int r = 0; r < 4; ++r)
          *(bf16*)(SM + SB + m*1024 + (lg*4+r)*16 + (n*2 + (lm>>3))*256 + (lm&7)*2)
            = (bf16)acc[m][n][r];
    FENCE();
#pragma unroll
    for (int m = 0; m < 4; ++m)
      qf[m] = *(const bf16x8*)(SM + SB + m*1024 + lane*16);
    FENCE();
#pragma unroll
    for (int m = 0; m < 4; ++m)
#pragma unroll
      for (int n = 0; n < 2; ++n)
#pragma unroll
        for (int r = 0; r < 4; ++r)
          *(bf16*)(SM + SB + m*1024 + (lg*4+r)*16 + (n*2 + (lm>>3))*256 + (lm&7)*2)
            = (bf16)acc[m][2+n][r];
    FENCE();
#pragma unroll
    for (int m = 0; m < 4; ++m)
      kf[m] = *(const bf16x8*)(SM + SB + m*1024 + lane*16);
    FENCE();
  }

  // ---- QKV pass1: v (d 0..32) for this head
  {
    const int jv[2] = { 512 + h*32 + lm, 512 + h*32 + 16 + lm };
    f32x4 vacc[4][2] = {};
#pragma unroll
    for (int kk = 0; kk < 8; ++kk) {
      const int ko = kk*32 + lk;
      bf16x8 a[4], bb[2];
#pragma unroll
      for (int m = 0; m < 4; ++m) {
        const int t = m*16 + lm;
        a[m] = *(const bf16x8*)(SM + ((t*512 + ko*2) ^ ((t&7)<<4)));
      }
#pragma unroll
      for (int n = 0; n < 2; ++n)
        bb[n] = *(const bf16x8*)(qkv_wb + jv[n]*256 + ko);
#pragma unroll
      for (int m = 0; m < 4; ++m)
#pragma unroll
        for (int n = 0; n < 2; ++n)
          vacc[m][n] = MFMA16(a[m], bb[n], vacc[m][n]);
    }
    float bj[2] = { qkv_b[jv[0]], qkv_b[jv[1]] };
    // bounce v -> B-frag layout: frag f = nf*2 + ks
#pragma unroll
    for (int m = 0; m < 4; ++m)
#pragma unroll
      for (int n = 0; n < 2; ++n)
#pragma unroll
        for (int r = 0; r < 4; ++r)
          *(bf16*)(SM + SB + (n*2 + (m>>1))*1024 + lm*16
                   + ((m&1)*2 + ((lg*4+r)>>3))*256 + ((lg*4+r)&7)*2)
            = (bf16)(vacc[m][n][r] + bj[n]);
    FENCE();
#pragma unroll
    for (int nf = 0; nf < 2; ++nf)
#pragma unroll
      for (int ks = 0; ks < 2; ++ks)
        vb[nf][ks] = *(const bf16x8*)(SM + SB + (nf*2+ks)*1024 + lane*16);
    FENCE();
  }
  __syncthreads();   // B1: all waves done reading XA (x tile dead)

  // ---- QK^T + bias + mask + softmax (all in-register)
  f32x4 s[4][4];
#pragma unroll
  for (int m = 0; m < 4; ++m)
#pragma unroll
    for (int n = 0; n < 4; ++n) {
      f32x4 z = {};
      s[m][n] = MFMA16(qf[m], kf[n], z);
    }
#pragma unroll
  for (int n = 0; n < 4; ++n) {
    const int ct = n*16 + lm;
    const int idc = ((wy==7) ? (((ct>>3) < 4) ? 1 : 2) : 0) * 3
                  + ((wx==7) ? (((ct&7)  < 4) ? 1 : 2) : 0);
#pragma unroll
    for (int m = 0; m < 4; ++m) {
      const float4 bt = *(const float4*)(bias_t + h*4096 + ct*64 + m*16 + lg*4);
      const float btv[4] = { bt.x, bt.y, bt.z, bt.w };
#pragma unroll
      for (int r = 0; r < 4; ++r) {
        const int rt = m*16 + lg*4 + r;
        const int idr = ((wy==7) ? (((rt>>3) < 4) ? 1 : 2) : 0) * 3
                      + ((wx==7) ? (((rt&7)  < 4) ? 1 : 2) : 0);
        float add = btv[r];
        if (idr != idc) add -= 100.0f;
        s[m][n][r] += add;
      }
    }
  }
#pragma unroll
  for (int m = 0; m < 4; ++m)
#pragma unroll
    for (int r = 0; r < 4; ++r) {
      float v0 = s[m][0][r], v1 = s[m][1][r], v2 = s[m][2][r], v3 = s[m][3][r];
      float mx = fmaxf(fmaxf(v0, v1), fmaxf(v2, v3));
      mx = fmaxf(mx, __shfl_xor(mx, 1));
      mx = fmaxf(mx, __shfl_xor(mx, 2));
      mx = fmaxf(mx, __shfl_xor(mx, 4));
      mx = fmaxf(mx, __shfl_xor(mx, 8));
      v0 = expf(v0 - mx); v1 = expf(v1 - mx); v2 = expf(v2 - mx); v3 = expf(v3 - mx);
      float sm = v0 + v1 + v2 + v3;
      sm += __shfl_xor(sm, 1);
      sm += __shfl_xor(sm, 2);
      sm += __shfl_xor(sm, 4);
      sm += __shfl_xor(sm, 8);
      const float inv = 1.0f / sm;
      s[m][0][r] = v0*inv; s[m][1][r] = v1*inv; s[m][2][r] = v2*inv; s[m][3][r] = v3*inv;
    }

  // ---- PV through strip in two 32-row halves
  f32x4 yacc[4][2] = {};
#pragma unroll
  for (int mh = 0; mh < 2; ++mh) {
#pragma unroll
    for (int ml = 0; ml < 2; ++ml)
#pragma unroll
      for (int n = 0; n < 4; ++n)
#pragma unroll
        for (int r = 0; r < 4; ++r)
          *(bf16*)(SM + SB + (ml*2 + (n>>1))*1024 + (lg*4+r)*16
                   + ((n&1)*2 + (lm>>3))*256 + (lm&7)*2)
            = (bf16)s[mh*2+ml][n][r];
    FENCE();
    bf16x8 pa[2][2];
#pragma unroll
    for (int ml = 0; ml < 2; ++ml)
#pragma unroll
      for (int ks = 0; ks < 2; ++ks)
        pa[ml][ks] = *(const bf16x8*)(SM + SB + (ml*2+ks)*1024 + lane*16);
    FENCE();
#pragma unroll
    for (int ml = 0; ml < 2; ++ml)
#pragma unroll
      for (int ks = 0; ks < 2; ++ks)
#pragma unroll
        for (int nf = 0; nf < 2; ++nf)
          yacc[mh*2+ml][nf] = MFMA16(pa[ml][ks], vb[nf][ks], yacc[mh*2+ml][nf]);
  }

  // ---- y (head h) -> y_all in XA area, cols h*32..h*32+32
#pragma unroll
  for (int m = 0; m < 4; ++m)
#pragma unroll
    for (int nf = 0; nf < 2; ++nf)
#pragma unroll
      for (int r = 0; r < 4; ++r) {
        const int t = m*16 + lg*4 + r;
        const int c = h*32 + nf*16 + lm;
        *(bf16*)(SM + ((t*512 + c*2) ^ ((t&7)<<4))) = (bf16)yacc[m][nf][r];
      }
  __syncthreads();   // B2

  // ---- proj: wave covers 32 cols, K=256
  f32x4 pacc[4][2] = {};
#pragma unroll
  for (int kk = 0; kk < 8; ++kk) {
    const int ko = kk*32 + lk;
    bf16x8 a[4], bb[2];
#pragma unroll
    for (int m = 0; m < 4; ++m) {
      const int t = m*16 + lm;
      a[m] = *(const bf16x8*)(SM + ((t*512 + ko*2) ^ ((t&7)<<4)));
    }
#pragma unroll
    for (int n = 0; n < 2; ++n) {
      const int j = wv*32 + n*16 + lm;
      bb[n] = *(const bf16x8*)(proj_wb + j*256 + ko);
    }
#pragma unroll
    for (int m = 0; m < 4; ++m)
#pragma unroll
      for (int n = 0; n < 2; ++n)
        pacc[m][n] = MFMA16(a[m], bb[n], pacc[m][n]);
  }
  __syncthreads();   // B3: y_all + strips dead -> Y2 overlay 0..64K

  // ---- Y2 fp32 [64][256] with 2-key XOR swizzle
#pragma unroll
  for (int n = 0; n < 2; ++n) {
    const int j = wv*32 + n*16 + lm;
    const float bj = proj_b[j];
#pragma unroll
    for (int m = 0; m < 4; ++m)
#pragma unroll
      for (int r = 0; r < 4; ++r) {
        const int t = m*16 + lg*4 + r;
        *(float*)(SM + t*1024 + ((j*4) ^ (((t&7) ^ ((j>>5)&7))<<4))) = pacc[m][n][r] + bj;
      }
  }
  __syncthreads();   // B4

  // ---- LN(norm1) + shortcut, scatter to x1 at unshifted position (8 thr/row)
  {
    const int t8 = tid >> 3, sub = tid & 7;
    float sum = 0.f, ssq = 0.f;
    float4 fv[8];
#pragma unroll
    for (int i = 0; i < 8; ++i) {
      fv[i] = *(const float4*)(SM + t8*1024 + ((sub*128 + i*16) ^ (((t8&7) ^ sub)<<4)));
      sum += fv[i].x + fv[i].y + fv[i].z + fv[i].w;
      ssq += fv[i].x*fv[i].x + fv[i].y*fv[i].y + fv[i].z*fv[i].z + fv[i].w*fv[i].w;
    }
    sum += __shfl_xor(sum, 1); sum += __shfl_xor(sum, 2); sum += __shfl_xor(sum, 4);
    ssq += __shfl_xor(ssq, 1); ssq += __shfl_xor(ssq, 2); ssq += __shfl_xor(ssq, 4);
    const float mu  = sum * (1.0f/256.0f);
    const float var = ssq * (1.0f/256.0f) - mu*mu;
    const float inv = rsqrtf(var + 1e-5f);
    const int iy = t8 >> 3, ix = t8 & 7;
    const int gh = (wy*8 + iy + 4) & 63, gw = (wx*8 + ix + 4) & 63;
    const size_t grow = (size_t)(b*4096 + gh*64 + gw) * 256;
#pragma unroll
    for (int i = 0; i < 8; ++i) {
      const int c = sub*32 + i*4;
      const float4 w4 = *(const float4*)(n1w + c);
      const float4 b4 = *(const float4*)(n1b + c);
      const float4 xr = *(const float4*)(x + grow + c);
      float4 o;
      o.x = (fv[i].x - mu)*inv*w4.x + b4.x + xr.x;
      o.y = (fv[i].y - mu)*inv*w4.y + b4.y + xr.y;
      o.z = (fv[i].z - mu)*inv*w4.z + b4.z + xr.z;
      o.w = (fv[i].w - mu)*inv*w4.w + b4.w + xr.w;
      *(float4*)(x1 + grow + c) = o;
    }
  }
}

// ---------------- fused MLP: fc1 + GELU + fc2 + LN2 + residual -> out ----------------
// one block per 64 tokens; h chunked 4x256 through LDS; 64KB -> 2 blocks/CU.
__launch_bounds__(512, 4)
__global__ void k_mlp(const float* __restrict__ x1,
                      const bf16* __restrict__ fc1_wb, const float* __restrict__ fc1_b,
                      const bf16* __restrict__ fc2_wb, const float* __restrict__ fc2_b,
                      const float* __restrict__ n2w, const float* __restrict__ n2b,
                      float* __restrict__ out) {
  __shared__ __align__(16) unsigned char SM[65536];   // XA 0..32K, HS 32K..64K, Y2 overlay 0..64K
  const int tid = threadIdx.x;
  const int wv = tid >> 6, lane = tid & 63;
  const int lm = lane & 15, lg = lane >> 4, lk = lg << 3;
  const int mb = blockIdx.x;
  const int HS = 32768;

  // stage x1 tile -> XA bf16
  {
    const int t = tid >> 3, q8 = tid & 7;
    const float* src = x1 + (size_t)(mb*64 + t) * 256 + q8*32;
#pragma unroll
    for (int i = 0; i < 4; ++i) {
      float4 f0 = *(const float4*)(src + i*8);
      float4 f1 = *(const float4*)(src + i*8 + 4);
      *(bf16x8*)(SM + ((t*512 + (q8*32 + i*8)*2) ^ ((t&7)<<4))) = cvt8(f0, f1);
    }
  }
  __syncthreads();

  f32x4 acc2[4][2] = {};
#pragma unroll 1
  for (int kc = 0; kc < 4; ++kc) {
    // fc1: h chunk cols kc*256 + wv*32 + ...
    f32x4 acc1[4][2] = {};
#pragma unroll
    for (int kk = 0; kk < 8; ++kk) {
      const int ko = kk*32 + lk;
      bf16x8 a[4], bb[2];
#pragma unroll
      for (int m = 0; m < 4; ++m) {
        const int t = m*16 + lm;
        a[m] = *(const bf16x8*)(SM + ((t*512 + ko*2) ^ ((t&7)<<4)));
      }
#pragma unroll
      for (int n = 0; n < 2; ++n) {
        const int j = kc*256 + wv*32 + n*16 + lm;
        bb[n] = *(const bf16x8*)(fc1_wb + j*256 + ko);
      }
#pragma unroll
      for (int m = 0; m < 4; ++m)
#pragma unroll
        for (int n = 0; n < 2; ++n)
          acc1[m][n] = MFMA16(a[m], bb[n], acc1[m][n]);
    }
    // GELU + bias -> HS
#pragma unroll
    for (int n = 0; n < 2; ++n) {
      const float bj = fc1_b[kc*256 + wv*32 + n*16 + lm];
      const int cb = wv*64 + n*32 + lm*2;          // byte col in [64][512B] row
#pragma unroll
      for (int m = 0; m < 4; ++m)
#pragma unroll
        for (int r = 0; r < 4; ++r) {
          const int t = m*16 + lg*4 + r;
          float v = acc1[m][n][r] + bj;
          v = 0.5f * v * (1.0f + erff(v * 0.70710678118654752f));
          *(bf16*)(SM + HS + ((t*512 + cb) ^ ((t&7)<<4))) = (bf16)v;
        }
    }
    __syncthreads();
    // fc2 partial: K-chunk kc
#pragma unroll
    for (int kk = 0; kk < 8; ++kk) {
      const int ko = kk*32 + lk;
      bf16x8 a[4], bb[2];
#pragma unroll
      for (int m = 0; m < 4; ++m) {
        const int t = m*16 + lm;
        a[m] = *(const bf16x8*)(SM + HS + ((t*512 + ko*2) ^ ((t&7)<<4)));
      }
#pragma unroll
      for (int n = 0; n < 2; ++n) {
        const int j = wv*32 + n*16 + lm;
        bb[n] = *(const bf16x8*)(fc2_wb + (size_t)j*1024 + kc*256 + ko);
      }
#pragma unroll
      for (int m = 0; m < 4; ++m)
#pragma unroll
        for (int n = 0; n < 2; ++n)
          acc2[m][n] = MFMA16(a[m], bb[n], acc2[m][n]);
    }
    __syncthreads();   // HS dead (next kc overwrites); after kc=3 this guards Y2 overlay
  }

  // Y2 fp32 [64][256] 2-key swizzle overlay at 0..64K
#pragma unroll
  for (int n = 0; n < 2; ++n) {
    const int j = wv*32 + n*16 + lm;
    const float bj = fc2_b[j];
#pragma unroll
    for (int m = 0; m < 4; ++m)
#pragma unroll
      for (int r = 0; r < 4; ++r) {
        const int t = m*16 + lg*4 + r;
        *(float*)(SM + t*1024 + ((j*4) ^ (((t&7) ^ ((j>>5)&7))<<4))) = acc2[m][n][r] + bj;
      }
  }
  __syncthreads();

  // LN(norm2) + residual -> out
  {
    const int t8 = tid >> 3, sub = tid & 7;
    float sum = 0.f, ssq = 0.f;
    float4 fv[8];
#pragma unroll
    for (int i = 0; i < 8; ++i) {
      fv[i] = *(const float4*)(SM + t8*1024 + ((sub*128 + i*16) ^ (((t8&7) ^ sub)<<4)));
      sum += fv[i].x + fv[i].y + fv[i].z + fv[i].w;
      ssq += fv[i].x*fv[i].x + fv[i].y*fv[i].y + fv[i].z*fv[i].z + fv[i].w*fv[i].w;
    }
    sum += __shfl_xor(sum, 1); sum += __shfl_xor(sum, 2); sum += __shfl_xor(sum, 4);
    ssq += __shfl_xor(ssq, 1); ssq += __shfl_xor(ssq, 2); ssq += __shfl_xor(ssq, 4);
    const float mu  = sum * (1.0f/256.0f);
    const float var = ssq * (1.0f/256.0f) - mu*mu;
    const float inv = rsqrtf(var + 1e-5f);
    const size_t grow = (size_t)(mb*64 + t8) * 256;
#pragma unroll
    for (int i = 0; i < 8; ++i) {
      const int c = sub*32 + i*4;
      const float4 w4 = *(const float4*)(n2w + c);
      const float4 b4 = *(const float4*)(n2b + c);
      const float4 xr = *(const float4*)(x1 + grow + c);
      float4 o;
      o.x = (fv[i].x - mu)*inv*w4.x + b4.x + xr.x;
      o.y = (fv[i].y - mu)*inv*w4.y + b4.y + xr.y;
      o.z = (fv[i].z - mu)*inv*w4.z + b4.z + xr.z;
      o.w = (fv[i].w - mu)*inv*w4.w + b4.w + xr.w;
      *(float4*)(out + grow + c) = o;
    }
  }
}

extern "C" void kernel_launch(void* const* d_in, const int* in_sizes, int n_in,
                              void* d_out, int out_size, void* d_ws, size_t ws_size,
                              hipStream_t stream) {
  const float* x      = (const float*)d_in[0];
  const float* qkv_w  = (const float*)d_in[1];
  const float* qkv_b  = (const float*)d_in[2];
  const float* nq_w   = (const float*)d_in[3];
  const float* nk_w   = (const float*)d_in[4];
  const float* cpb_w1 = (const float*)d_in[5];
  const float* cpb_b1 = (const float*)d_in[6];
  const float* cpb_w2 = (const float*)d_in[7];
  const float* proj_w = (const float*)d_in[8];
  const float* proj_b = (const float*)d_in[9];
  const float* n1w    = (const float*)d_in[10];
  const float* n1b    = (const float*)d_in[11];
  const float* fc1_w  = (const float*)d_in[12];
  const float* fc1_b  = (const float*)d_in[13];
  const float* fc2_w  = (const float*)d_in[14];
  const float* fc2_b  = (const float*)d_in[15];
  const float* n2w    = (const float*)d_in[16];
  const float* n2b    = (const float*)d_in[17];

  char* ws = (char*)d_ws;
  float* x1      = (float*)(ws);                   // 33554432 B
  bf16*  qkv_wb  = (bf16*) (ws + 33554432);        //   393216 B
  bf16*  proj_wb = (bf16*) (ws + 33947648);        //   131072 B
  bf16*  fc1_wb  = (bf16*) (ws + 34078720);        //   524288 B
  bf16*  fc2_wb  = (bf16*) (ws + 34603008);        //   524288 B
  float* bias_t  = (float*)(ws + 35127296);        //   131072 B
  float* tab_g   = (float*)(ws + 35258368);        //     7200 B

  prep_weights<<<1024, 256, 0, stream>>>(qkv_w, proj_w, fc1_w, fc2_w,
                                         qkv_wb, proj_wb, fc1_wb, fc2_wb);
  prep_tab<<<225, 64, 0, stream>>>(cpb_w1, cpb_b1, cpb_w2, tab_g);
  prep_expand<<<128, 256, 0, stream>>>(tab_g, bias_t);
  k_attn<<<512, 512, 0, stream>>>(x, qkv_wb, qkv_b, nq_w, nk_w,
                                  proj_wb, proj_b, n1w, n1b, bias_t, x1);
  k_mlp<<<512, 512, 0, stream>>>(x1, fc1_wb, fc1_b, fc2_wb, fc2_b, n2w, n2b, (float*)d_out);
}